// Round 11
// baseline (254.463 us; speedup 1.0000x reference)
//
#include <hip/hip_runtime.h>
#include <math.h>

#define Bb 2
#define Ss 128
#define Hh 768
#define Cc 5
#define Mm 256       // Bb*Ss
#define NEGV -1024.0f
#define SCALE 2.8853900817779268f   // 2/ln(2): stored pre-scaled so exp2(hp'+ha') = e^{2x}

// haTb: bf16 [b][c][hp8][a][h&7], hp8=h>>3 in [0,96). ushort offset:
//   ((b*5+c)*96 + hp8)*1024 + a*8 + (h&7)
#define PT 4
#define NPT (Mm / PT)          // 64 p-tiles
#define NBLK (NPT * Cc * 4)    // 1280 = 5 blocks/CU exactly

typedef __attribute__((ext_vector_type(8))) short bf16x8;
typedef __attribute__((ext_vector_type(4))) float f32x4;
typedef unsigned short ushort;

__device__ __forceinline__ unsigned pack_hi16(float hi, float lo) {
    return (__float_as_uint(hi) & 0xFFFF0000u) | (__float_as_uint(lo) >> 16);
}
__device__ __forceinline__ bf16x8 pack_bf16x8(float4 lo, float4 hi) {
    union { bf16x8 v; unsigned u[4]; } r;
    r.u[0] = pack_hi16(lo.y, lo.x);
    r.u[1] = pack_hi16(lo.w, lo.z);
    r.u[2] = pack_hi16(hi.y, hi.x);
    r.u[3] = pack_hi16(hi.w, hi.z);
    return r.v;
}

// ---------------- Kernel 1: bf16 MFMA GEMM -> hp (fp32) + haTb (bf16, transposed) ----------------
// bm==0 blocks also do setup: zero Lpart/cnt/accum, compute maskneg_g and swr_g.
__global__ __launch_bounds__(256)
void gemm_mfma(const float* __restrict__ X,
               const float* __restrict__ Wprd,
               const float* __restrict__ Warg,
               const float* __restrict__ bprd,
               const float* __restrict__ barg,
               const int* __restrict__ ng,
               const int* __restrict__ att,
               const float* __restrict__ Wout,
               float* __restrict__ hp_out,
               ushort* __restrict__ haTb,
               float* __restrict__ Lpart,
               float* __restrict__ maskneg_g,
               float* __restrict__ swr_g,
               float* __restrict__ accum,
               unsigned* __restrict__ cnt)
{
    __shared__ float redw[4];
    const int bm   = blockIdx.x;          // 0..3   (64 rows)
    const int bn   = blockIdx.y;          // 0..143 (32 cols)
    const int tid  = threadIdx.x;

    if (bm == 0) {   // setup work, distributed over 144 blocks x 256 threads
        const int g = bn * 256 + tid;     // 0..36863
        for (int i = g; i < NPT * Cc * PT * Ss; i += 144 * 256) Lpart[i] = 0.f;
        if (g < Mm * Ss) {
            const int bp = g >> 7, aa = g & 127, bI = bp >> 7;
            int any = 0;
            if (att[bI * Ss + aa] > 0) {
                const int* ngp = ng + (size_t)bp * Cc * Ss + aa;
                #pragma unroll
                for (int cc2 = 0; cc2 < Cc; ++cc2) any |= ngp[cc2 * Ss];
            }
            maskneg_g[g] = any ? 0.0f : NEGV;
        }
        if (g < NPT * Cc) cnt[g] = 0u;
        if (g == NPT * Cc) { accum[0] = 0.f; accum[1] = 0.f; }
        if (g == NPT * Cc + 1) ((unsigned*)accum)[2] = 0u;
        if (bn >= 139) {                  // 5 blocks compute swr_g[c]
            const int c2 = bn - 139;
            float s = 0.f;
            for (int i = tid; i < Hh; i += 256) s += Wout[c2 * Hh + i];
            #pragma unroll
            for (int off = 32; off; off >>= 1) s += __shfl_xor(s, off, 64);
            if ((tid & 63) == 0) redw[tid >> 6] = s;
            __syncthreads();
            if (tid == 0) swr_g[c2] = redw[0] + redw[1] + redw[2] + redw[3];
        }
    }

    const int wave = tid >> 6;
    const int lane = tid & 63;
    const int l16  = lane & 15;
    const int quad = lane >> 4;

    const float* Wsrc; const float* bsrc;
    const int nb = bn * 32;
    if (nb < Hh) { Wsrc = Wprd + (size_t)nb * Hh;        bsrc = bprd + nb; }
    else         { Wsrc = Warg + (size_t)(nb - Hh) * Hh; bsrc = barg + (nb - Hh); }

    const int m_g = bm * 64 + wave * 16 + l16;
    const float* arow  = X    + (size_t)m_g * Hh + quad * 8;
    const float* brow0 = Wsrc + (size_t)l16 * Hh + quad * 8;
    const float* brow1 = Wsrc + (size_t)(16 + l16) * Hh + quad * 8;

    f32x4 acc0 = {0.f, 0.f, 0.f, 0.f};
    f32x4 acc1 = {0.f, 0.f, 0.f, 0.f};

    float4 a0  = *(const float4*)(arow);
    float4 a1  = *(const float4*)(arow + 4);
    float4 b00 = *(const float4*)(brow0);
    float4 b01 = *(const float4*)(brow0 + 4);
    float4 b10 = *(const float4*)(brow1);
    float4 b11 = *(const float4*)(brow1 + 4);

    #pragma unroll 4
    for (int k = 0; k < Hh; k += 32) {
        const int kn = (k + 32 < Hh) ? k + 32 : 0;
        float4 na0  = *(const float4*)(arow  + kn);
        float4 na1  = *(const float4*)(arow  + kn + 4);
        float4 nb00 = *(const float4*)(brow0 + kn);
        float4 nb01 = *(const float4*)(brow0 + kn + 4);
        float4 nb10 = *(const float4*)(brow1 + kn);
        float4 nb11 = *(const float4*)(brow1 + kn + 4);
        bf16x8 af  = pack_bf16x8(a0,  a1);
        bf16x8 bf0 = pack_bf16x8(b00, b01);
        bf16x8 bf1 = pack_bf16x8(b10, b11);
        acc0 = __builtin_amdgcn_mfma_f32_16x16x32_bf16(af, bf0, acc0, 0, 0, 0);
        acc1 = __builtin_amdgcn_mfma_f32_16x16x32_bf16(af, bf1, acc1, 0, 0, 0);
        a0 = na0; a1 = na1; b00 = nb00; b01 = nb01; b10 = nb10; b11 = nb11;
    }

    const float sb0 = SCALE * bsrc[l16];
    const float sb1 = SCALE * bsrc[16 + l16];
    const int row = bm * 64 + wave * 16 + quad * 4;

    if (nb < Hh) {   // hp: row-major fp32 [m][h]
        #pragma unroll
        for (int r = 0; r < 4; ++r) {
            const int mm = row + r;
            hp_out[(size_t)mm * Hh + nb + l16]      = SCALE * acc0[r] + sb0;
            hp_out[(size_t)mm * Hh + nb + 16 + l16] = SCALE * acc1[r] + sb1;
        }
    } else {         // ha -> haTb bf16 [b][c][h>>3][a][h&7]
        const int q  = nb - Hh;
        const int cU = q / Hh;
        const int h0 = q % Hh;
        const int hA = h0 + l16;
        const int hB = h0 + 16 + l16;
        #pragma unroll
        for (int r = 0; r < 4; ++r) {
            const int mm = row + r;
            const int bI = mm >> 7, aI = mm & 127;
            const size_t base = ((size_t)(bI * Cc + cU) * 96) * 1024 + (size_t)aI * 8;
            const float v0 = SCALE * acc0[r] + sb0;
            const float v1 = SCALE * acc1[r] + sb1;
            haTb[base + (size_t)(hA >> 3) * 1024 + (hA & 7)] = (ushort)(__float_as_uint(v0) >> 16);
            haTb[base + (size_t)(hB >> 3) * 1024 + (hB & 7)] = (ushort)(__float_as_uint(v1) >> 16);
        }
    }
}

// ---------------- Kernel 2: biaffine, PT=4, h-split-4, bf16 ha stream ----------------
// Grid 1280 = (c,hq)-major: bx = ((c*4+hq)*64 + pt). Block 256: tid = hs*128 + a;
// thread streams 96 h (12 uint4 bf16-packs) for 4 p-rows. sched_barrier ping-pong.
#define SBAR __builtin_amdgcn_sched_barrier(0);

#define LG4(R, g) \
    R##0 = hap4[((g)*4 + 0) * 128]; R##1 = hap4[((g)*4 + 1) * 128]; \
    R##2 = hap4[((g)*4 + 2) * 128]; R##3 = hap4[((g)*4 + 3) * 128];

#define CONS1(u, hx) { \
    const float f0 = __uint_as_float((u).x << 16); \
    const float f1 = __uint_as_float((u).x & 0xFFFF0000u); \
    const float f2 = __uint_as_float((u).y << 16); \
    const float f3 = __uint_as_float((u).y & 0xFFFF0000u); \
    const float f4 = __uint_as_float((u).z << 16); \
    const float f5 = __uint_as_float((u).z & 0xFFFF0000u); \
    const float f6 = __uint_as_float((u).w << 16); \
    const float f7 = __uint_as_float((u).w & 0xFFFF0000u); \
    const float4 wA = *(const float4*)(wc_s + (hx)); \
    const float4 wB = *(const float4*)(wc_s + (hx) + 4); \
    _Pragma("unroll") \
    for (int p = 0; p < PT; ++p) { \
        const float4 hA = *(const float4*)(&hp_s[p][hx]); \
        const float4 hB = *(const float4*)(&hp_s[p][(hx) + 4]); \
        float r; \
        r = __builtin_amdgcn_rcpf(__builtin_amdgcn_exp2f(hA.x + f0) + 1.0f); acA[p] = fmaf(wA.x, r, acA[p]); \
        r = __builtin_amdgcn_rcpf(__builtin_amdgcn_exp2f(hA.y + f1) + 1.0f); acB[p] = fmaf(wA.y, r, acB[p]); \
        r = __builtin_amdgcn_rcpf(__builtin_amdgcn_exp2f(hA.z + f2) + 1.0f); acA[p] = fmaf(wA.z, r, acA[p]); \
        r = __builtin_amdgcn_rcpf(__builtin_amdgcn_exp2f(hA.w + f3) + 1.0f); acB[p] = fmaf(wA.w, r, acB[p]); \
        r = __builtin_amdgcn_rcpf(__builtin_amdgcn_exp2f(hB.x + f4) + 1.0f); acA[p] = fmaf(wB.x, r, acA[p]); \
        r = __builtin_amdgcn_rcpf(__builtin_amdgcn_exp2f(hB.y + f5) + 1.0f); acB[p] = fmaf(wB.y, r, acB[p]); \
        r = __builtin_amdgcn_rcpf(__builtin_amdgcn_exp2f(hB.z + f6) + 1.0f); acA[p] = fmaf(wB.z, r, acA[p]); \
        r = __builtin_amdgcn_rcpf(__builtin_amdgcn_exp2f(hB.w + f7) + 1.0f); acB[p] = fmaf(wB.w, r, acB[p]); \
    } \
}

#define CG4(R, g) \
    CONS1(R##0, hs * 96 + ((g)*4 + 0) * 8) \
    CONS1(R##1, hs * 96 + ((g)*4 + 1) * 8) \
    CONS1(R##2, hs * 96 + ((g)*4 + 2) * 8) \
    CONS1(R##3, hs * 96 + ((g)*4 + 3) * 8)

__global__ __launch_bounds__(256, 5)
void biaffine_loss(const float* __restrict__ hp_all,
                   const ushort* __restrict__ haTb,
                   const float* __restrict__ Wout,
                   const float* __restrict__ Lpart_c,
                   const float* __restrict__ maskneg_g,
                   const float* __restrict__ swr_g,
                   const float* __restrict__ target,
                   float* __restrict__ out_logits,
                   float* __restrict__ accum,
                   float* __restrict__ out_loss,
                   float* __restrict__ Lpart,
                   unsigned* __restrict__ cnt)
{
    __shared__ float hp_s[PT][192];
    __shared__ float wc_s[192];
    __shared__ float partial[PT][Ss];
    __shared__ float redmax2[2];
    __shared__ float red32[2][3];
    __shared__ int isfin_s;

    const int bx  = blockIdx.x;
    const int chq = bx >> 6;             // 0..19
    const int pt  = bx & 63;             // 0..63
    const int c   = chq >> 2;            // 0..4
    const int hq  = chq & 3;             // 0..3
    const int bp0 = pt * PT;
    const int b   = bp0 >> 7;
    const int tid = threadIdx.x;
    const int a   = tid & (Ss - 1);
    const int hs  = tid >> 7;            // 0/1: h-subhalf (96 h each)
    const int lane = tid & 63;

    // stage hp window (4 rows x 192) + wc window into LDS
    #pragma unroll
    for (int p = 0; p < PT; ++p)
        if (tid < 192) hp_s[p][tid] = hp_all[(size_t)(bp0 + p) * Hh + hq * 192 + tid];
    if (tid < 192) wc_s[tid] = Wout[(size_t)c * Hh + hq * 192 + tid];
    __syncthreads();

    // ha stream: uint4 pack j at hap4[j*128], j in [0,12)
    const ushort* habase = haTb + ((size_t)(b * Cc + c) * 96 + hq * 24 + hs * 12) * 1024
                         + (size_t)a * 8;
    const uint4* hap4 = (const uint4*)habase;

    uint4 A0, A1, A2, A3, B0, B1, B2, B3;
    float acA[PT] = {0.f, 0.f, 0.f, 0.f};
    float acB[PT] = {0.f, 0.f, 0.f, 0.f};

    LG4(A, 0) SBAR
    LG4(B, 1) SBAR  CG4(A, 0) SBAR
    LG4(A, 2) SBAR  CG4(B, 1) SBAR
    CG4(A, 2)

    // combine hs halves
    if (hs == 1) {
        #pragma unroll
        for (int p = 0; p < PT; ++p) partial[p][a] = acA[p] + acB[p];
    }
    __syncthreads();
    if (hs == 0) {
        #pragma unroll
        for (int p = 0; p < PT; ++p) {
            const float bps = acA[p] + acB[p] + partial[p][a];
            atomicAdd(&Lpart[((size_t)(pt * Cc + c) * PT + p) * Ss + a], bps);
        }
    }
    __threadfence();
    __syncthreads();
    if (tid == 0) {
        const unsigned o = atomicAdd(&cnt[pt * Cc + c], 1u);
        isfin_s = (o == 3u);
    }
    __syncthreads();
    if (!isfin_s) return;        // block-uniform exit
    __threadfence();             // acquire: all 4 blocks' Lpart adds visible

    // ---- finisher: logits + log-softmax + loss for 4 rows ----
    const int act = (tid < Ss);
    const int wv  = (tid >> 6) & 1;
    const float swr = swr_g[c];
    float nsum = 0.f, dsum = 0.f;
    for (int p = 0; p < PT; ++p) {
        float lg = 0.f;
        if (act) {
            const float Lp = Lpart_c[((size_t)(pt * Cc + c) * PT + p) * Ss + a];
            lg = swr - 2.0f * Lp + maskneg_g[(size_t)(bp0 + p) * Ss + a];
            out_logits[((size_t)(bp0 + p) * Cc + c) * Ss + a] = lg;
            float mx = lg;
            #pragma unroll
            for (int off = 32; off; off >>= 1) mx = fmaxf(mx, __shfl_xor(mx, off, 64));
            if (lane == 0) redmax2[wv] = mx;
        }
        __syncthreads();
        const float rm = fmaxf(redmax2[0], redmax2[1]);
        if (act) {
            const float e  = __builtin_amdgcn_exp2f((lg - rm) * 1.4426950408889634f);
            const float tg = target[((size_t)(bp0 + p) * Cc + c) * Ss + a];
            float se = e, st = tg, sx = tg * lg;
            #pragma unroll
            for (int off = 32; off; off >>= 1) {
                se += __shfl_xor(se, off, 64);
                st += __shfl_xor(st, off, 64);
                sx += __shfl_xor(sx, off, 64);
            }
            if (lane == 0) { red32[wv][0] = se; red32[wv][1] = st; red32[wv][2] = sx; }
        }
        __syncthreads();
        if (tid == 0) {
            const float SE = red32[0][0] + red32[1][0];
            const float ST = red32[0][1] + red32[1][1];
            const float SX = red32[0][2] + red32[1][2];
            const float lse = rm + __builtin_amdgcn_logf(SE) * 0.6931471805599453f;
            nsum += lse * ST - SX;
            dsum += ST;
        }
        __syncthreads();         // protect redmax2/red32 reuse
    }
    if (tid == 0) {
        atomicAdd(&accum[0], nsum);
        atomicAdd(&accum[1], dsum);
        __threadfence();
        const unsigned o2 = atomicAdd((unsigned*)(accum + 2), 1u);
        if (o2 == (unsigned)(NPT * Cc - 1)) {
            const float n = atomicAdd(&accum[0], 0.0f);
            const float d = atomicAdd(&accum[1], 0.0f);
            out_loss[0] = n / d;
        }
    }
}

extern "C" void kernel_launch(void* const* d_in, const int* in_sizes, int n_in,
                              void* d_out, int out_size, void* d_ws, size_t ws_size,
                              hipStream_t stream) {
    const float* seq    = (const float*)d_in[0];
    const int*   att    = (const int*)  d_in[1];
    const int*   ng     = (const int*)  d_in[2];
    const float* target = (const float*)d_in[3];
    const float* Wprd   = (const float*)d_in[4];
    const float* bprd   = (const float*)d_in[5];
    const float* Warg   = (const float*)d_in[6];
    const float* barg   = (const float*)d_in[7];
    const float* Wout   = (const float*)d_in[8];

    float* out       = (float*)d_out;
    float*  base     = (float*)d_ws;
    float*  hp_out   = base;                                   // 196608 floats
    ushort* haTb     = (ushort*)(base + 196608);               // 983040 ushorts (491520 f)
    float*  Lpart    = base + 196608 + 491520;                 // 163840 floats
    float*  maskng   = Lpart + 163840;                         // 32768 floats
    float*  swr_g    = maskng + 32768;                         // 5 floats
    float*  accum    = swr_g + 8;                              // 3 slots
    unsigned* cnt    = (unsigned*)(accum + 3);                 // 320 uints

    gemm_mfma<<<dim3(4, 144), 256, 0, stream>>>(seq, Wprd, Warg, bprd, barg,
                                                ng, att, Wout,
                                                hp_out, haTb, Lpart, maskng, swr_g,
                                                accum, cnt);
    biaffine_loss<<<dim3(NBLK), 256, 0, stream>>>(hp_out, haTb, Wout,
                                                  Lpart, maskng, swr_g, target,
                                                  out + 1, accum, out, Lpart, cnt);
}

// Round 12
// 174.203 us; speedup vs baseline: 1.4607x; 1.4607x over previous
//
#include <hip/hip_runtime.h>
#include <math.h>

#define Bb 2
#define Ss 128
#define Hh 768
#define Cc 5
#define Mm 256       // Bb*Ss
#define NEGV -1024.0f
#define SCALE 2.8853900817779268f   // 2/ln(2): stored pre-scaled so exp2(hp'+ha') = e^{2x}

// haTb: bf16 [b][c][h8][a][h&7], h8=h>>3 in [0,96)
// ushort index = ((b*5+c)*96 + h8)*1024 + a*8 + (h&7)
#define PT 2
#define NBLK (Mm / PT * Cc)   // 640

typedef __attribute__((ext_vector_type(8))) short bf16x8;
typedef __attribute__((ext_vector_type(4))) float f32x4;
typedef unsigned short ushort;

__device__ __forceinline__ unsigned pack_hi16(float hi, float lo) {
    return (__float_as_uint(hi) & 0xFFFF0000u) | (__float_as_uint(lo) >> 16);
}
__device__ __forceinline__ bf16x8 pack_bf16x8(float4 lo, float4 hi) {
    union { bf16x8 v; unsigned u[4]; } r;
    r.u[0] = pack_hi16(lo.y, lo.x);
    r.u[1] = pack_hi16(lo.w, lo.z);
    r.u[2] = pack_hi16(hi.y, hi.x);
    r.u[3] = pack_hi16(hi.w, hi.z);
    return r.v;
}

// ---------------- Kernel 1: bf16 MFMA GEMM -> hp (fp32) + haTb (bf16, transposed) ----------------
__global__ __launch_bounds__(256)
void gemm_mfma(const float* __restrict__ X,
               const float* __restrict__ Wprd,
               const float* __restrict__ Warg,
               const float* __restrict__ bprd,
               const float* __restrict__ barg,
               float* __restrict__ hp_out,
               ushort* __restrict__ haTb,
               float* __restrict__ accum)
{
    if (blockIdx.x == 0 && blockIdx.y == 0 && threadIdx.x == 0) {
        accum[0] = 0.f; accum[1] = 0.f;
        ((unsigned*)accum)[2] = 0u;      // completion counter
    }
    const int bm   = blockIdx.x;          // 0..3   (64 rows)
    const int bn   = blockIdx.y;          // 0..143 (32 cols)
    const int wave = threadIdx.x >> 6;
    const int lane = threadIdx.x & 63;
    const int l16  = lane & 15;
    const int quad = lane >> 4;

    const float* Wsrc; const float* bsrc;
    const int nb = bn * 32;
    if (nb < Hh) { Wsrc = Wprd + (size_t)nb * Hh;        bsrc = bprd + nb; }
    else         { Wsrc = Warg + (size_t)(nb - Hh) * Hh; bsrc = barg + (nb - Hh); }

    const int m_g = bm * 64 + wave * 16 + l16;
    const float* arow  = X    + (size_t)m_g * Hh + quad * 8;
    const float* brow0 = Wsrc + (size_t)l16 * Hh + quad * 8;
    const float* brow1 = Wsrc + (size_t)(16 + l16) * Hh + quad * 8;

    f32x4 acc0 = {0.f, 0.f, 0.f, 0.f};
    f32x4 acc1 = {0.f, 0.f, 0.f, 0.f};

    float4 a0  = *(const float4*)(arow);
    float4 a1  = *(const float4*)(arow + 4);
    float4 b00 = *(const float4*)(brow0);
    float4 b01 = *(const float4*)(brow0 + 4);
    float4 b10 = *(const float4*)(brow1);
    float4 b11 = *(const float4*)(brow1 + 4);

    #pragma unroll 4
    for (int k = 0; k < Hh; k += 32) {
        const int kn = (k + 32 < Hh) ? k + 32 : 0;
        float4 na0  = *(const float4*)(arow  + kn);
        float4 na1  = *(const float4*)(arow  + kn + 4);
        float4 nb00 = *(const float4*)(brow0 + kn);
        float4 nb01 = *(const float4*)(brow0 + kn + 4);
        float4 nb10 = *(const float4*)(brow1 + kn);
        float4 nb11 = *(const float4*)(brow1 + kn + 4);
        bf16x8 af  = pack_bf16x8(a0,  a1);
        bf16x8 bf0 = pack_bf16x8(b00, b01);
        bf16x8 bf1 = pack_bf16x8(b10, b11);
        acc0 = __builtin_amdgcn_mfma_f32_16x16x32_bf16(af, bf0, acc0, 0, 0, 0);
        acc1 = __builtin_amdgcn_mfma_f32_16x16x32_bf16(af, bf1, acc1, 0, 0, 0);
        a0 = na0; a1 = na1; b00 = nb00; b01 = nb01; b10 = nb10; b11 = nb11;
    }

    const float sb0 = SCALE * bsrc[l16];
    const float sb1 = SCALE * bsrc[16 + l16];
    const int row = bm * 64 + wave * 16 + quad * 4;

    if (nb < Hh) {   // hp: row-major fp32 [m][h]
        #pragma unroll
        for (int r = 0; r < 4; ++r) {
            const int mm = row + r;
            hp_out[(size_t)mm * Hh + nb + l16]      = SCALE * acc0[r] + sb0;
            hp_out[(size_t)mm * Hh + nb + 16 + l16] = SCALE * acc1[r] + sb1;
        }
    } else {         // ha -> haTb bf16 [b][c][h>>3][a][h&7]
        const int q  = nb - Hh;
        const int cU = q / Hh;
        const int h0 = q % Hh;
        const int hA = h0 + l16;
        const int hB = h0 + 16 + l16;
        #pragma unroll
        for (int r = 0; r < 4; ++r) {
            const int mm = row + r;
            const int bI = mm >> 7, aI = mm & 127;
            const size_t base = ((size_t)(bI * Cc + cU) * 96) * 1024 + (size_t)aI * 8;
            const float v0 = SCALE * acc0[r] + sb0;
            const float v1 = SCALE * acc1[r] + sb1;
            haTb[base + (size_t)(hA >> 3) * 1024 + (hA & 7)] = (ushort)(__float_as_uint(v0) >> 16);
            haTb[base + (size_t)(hB >> 3) * 1024 + (hB & 7)] = (ushort)(__float_as_uint(v1) >> 16);
        }
    }
}

// ---------------- Kernel 2: biaffine, PT=2, bf16 ha stream, sched_barrier ping-pong ----------------
// Grid 640 = (p-tile, c). Block 256: tid = hh*128 + a; thread streams its 384-h half as
// 48 uint4 (8 bf16 h each) for PT=2 p-rows. 8-16 loads in flight, fine backend vmcnt.
#define SB __builtin_amdgcn_sched_barrier(0);

#define LOADG(R, g) \
    R##0 = hap4[((g)*8+0)*128]; R##1 = hap4[((g)*8+1)*128]; \
    R##2 = hap4[((g)*8+2)*128]; R##3 = hap4[((g)*8+3)*128]; \
    R##4 = hap4[((g)*8+4)*128]; R##5 = hap4[((g)*8+5)*128]; \
    R##6 = hap4[((g)*8+6)*128]; R##7 = hap4[((g)*8+7)*128];

#define C1(u, hx) { \
    const float f0 = __uint_as_float((u).x << 16); \
    const float f1 = __uint_as_float((u).x & 0xFFFF0000u); \
    const float f2 = __uint_as_float((u).y << 16); \
    const float f3 = __uint_as_float((u).y & 0xFFFF0000u); \
    const float f4 = __uint_as_float((u).z << 16); \
    const float f5 = __uint_as_float((u).z & 0xFFFF0000u); \
    const float f6 = __uint_as_float((u).w << 16); \
    const float f7 = __uint_as_float((u).w & 0xFFFF0000u); \
    const float4 wA = *(const float4*)(wc_s + (hx)); \
    const float4 wB = *(const float4*)(wc_s + (hx) + 4); \
    const float4 h0A = *(const float4*)(&hp_s[0][hx]); \
    const float4 h0B = *(const float4*)(&hp_s[0][(hx) + 4]); \
    const float4 h1A = *(const float4*)(&hp_s[1][hx]); \
    const float4 h1B = *(const float4*)(&hp_s[1][(hx) + 4]); \
    float r; \
    r = __builtin_amdgcn_rcpf(__builtin_amdgcn_exp2f(h0A.x + f0) + 1.0f); ac00 = fmaf(wA.x, r, ac00); \
    r = __builtin_amdgcn_rcpf(__builtin_amdgcn_exp2f(h0A.y + f1) + 1.0f); ac01 = fmaf(wA.y, r, ac01); \
    r = __builtin_amdgcn_rcpf(__builtin_amdgcn_exp2f(h0A.z + f2) + 1.0f); ac00 = fmaf(wA.z, r, ac00); \
    r = __builtin_amdgcn_rcpf(__builtin_amdgcn_exp2f(h0A.w + f3) + 1.0f); ac01 = fmaf(wA.w, r, ac01); \
    r = __builtin_amdgcn_rcpf(__builtin_amdgcn_exp2f(h0B.x + f4) + 1.0f); ac00 = fmaf(wB.x, r, ac00); \
    r = __builtin_amdgcn_rcpf(__builtin_amdgcn_exp2f(h0B.y + f5) + 1.0f); ac01 = fmaf(wB.y, r, ac01); \
    r = __builtin_amdgcn_rcpf(__builtin_amdgcn_exp2f(h0B.z + f6) + 1.0f); ac00 = fmaf(wB.z, r, ac00); \
    r = __builtin_amdgcn_rcpf(__builtin_amdgcn_exp2f(h0B.w + f7) + 1.0f); ac01 = fmaf(wB.w, r, ac01); \
    r = __builtin_amdgcn_rcpf(__builtin_amdgcn_exp2f(h1A.x + f0) + 1.0f); ac10 = fmaf(wA.x, r, ac10); \
    r = __builtin_amdgcn_rcpf(__builtin_amdgcn_exp2f(h1A.y + f1) + 1.0f); ac11 = fmaf(wA.y, r, ac11); \
    r = __builtin_amdgcn_rcpf(__builtin_amdgcn_exp2f(h1A.z + f2) + 1.0f); ac10 = fmaf(wA.z, r, ac10); \
    r = __builtin_amdgcn_rcpf(__builtin_amdgcn_exp2f(h1A.w + f3) + 1.0f); ac11 = fmaf(wA.w, r, ac11); \
    r = __builtin_amdgcn_rcpf(__builtin_amdgcn_exp2f(h1B.x + f4) + 1.0f); ac10 = fmaf(wB.x, r, ac10); \
    r = __builtin_amdgcn_rcpf(__builtin_amdgcn_exp2f(h1B.y + f5) + 1.0f); ac11 = fmaf(wB.y, r, ac11); \
    r = __builtin_amdgcn_rcpf(__builtin_amdgcn_exp2f(h1B.z + f6) + 1.0f); ac10 = fmaf(wB.z, r, ac10); \
    r = __builtin_amdgcn_rcpf(__builtin_amdgcn_exp2f(h1B.w + f7) + 1.0f); ac11 = fmaf(wB.w, r, ac11); \
}

#define CONSUMEG(R, g) \
    C1(R##0, hbase + ((g)*8+0)*8)  C1(R##1, hbase + ((g)*8+1)*8) \
    C1(R##2, hbase + ((g)*8+2)*8)  C1(R##3, hbase + ((g)*8+3)*8) \
    C1(R##4, hbase + ((g)*8+4)*8)  C1(R##5, hbase + ((g)*8+5)*8) \
    C1(R##6, hbase + ((g)*8+6)*8)  C1(R##7, hbase + ((g)*8+7)*8)

__global__ __launch_bounds__(256, 4)
void biaffine_loss(const float* __restrict__ hp_all,
                   const ushort* __restrict__ haTb,
                   const float* __restrict__ Wout,
                   const int* __restrict__ ng,
                   const int* __restrict__ att,
                   const float* __restrict__ target,
                   float* __restrict__ out_logits,
                   float* __restrict__ accum,
                   float* __restrict__ out_loss)
{
    __shared__ float hp_s[PT][Hh];
    __shared__ float wc_s[Hh];
    __shared__ float partial[PT][Ss];
    __shared__ float maskneg[PT][Ss];
    __shared__ float redmax[PT][2];
    __shared__ float red3[PT][2][3];
    __shared__ float swr_s;

    const int pt  = blockIdx.x / Cc;     // 0..127
    const int c   = blockIdx.x - pt * Cc;
    const int bp0 = pt * PT;
    const int b   = bp0 >> 7;
    const int tid = threadIdx.x;
    const int a   = tid & (Ss - 1);
    const int hh  = tid >> 7;            // 0/1: h-half (waves 0,1 -> 0; 2,3 -> 1)
    const int lane = tid & 63;

    // stage hp rows + wc row into LDS (coalesced); mask
    for (int i = tid; i < PT * Hh; i += 256) ((float*)hp_s)[i] = hp_all[(size_t)bp0 * Hh + i];
    for (int i = tid; i < Hh; i += 256)      wc_s[i] = Wout[(size_t)c * Hh + i];
    {
        const int p_i = tid >> 7;
        const int aa  = tid & (Ss - 1);
        int any = 0;
        if (att[b * Ss + aa] > 0) {
            const int* ngp = ng + (size_t)(bp0 + p_i) * Cc * Ss + aa;
            #pragma unroll
            for (int cc = 0; cc < Cc; ++cc) any |= ngp[cc * Ss];
        }
        maskneg[p_i][aa] = any ? 0.0f : NEGV;
    }
    __syncthreads();

    if (tid < 64) {    // wave 0: sumW[c]
        float s = 0.f;
        #pragma unroll
        for (int i = 0; i < Hh / 64; ++i) s += wc_s[tid + i * 64];
        #pragma unroll
        for (int off = 32; off; off >>= 1) s += __shfl_xor(s, off, 64);
        if (tid == 0) swr_s = s;
    }

    // thread's ha stream: uint4 j = 8 h values; index = (hh*48 + j)*128 + a
    const uint4* hap4 = (const uint4*)(haTb + ((size_t)(b * Cc + c) * 96) * 1024)
                      + (size_t)hh * 48 * 128 + a;
    const int hbase = hh * 384;

    uint4 A0, A1, A2, A3, A4, A5, A6, A7;
    uint4 B0, B1, B2, B3, B4, B5, B6, B7;
    float ac00 = 0.f, ac01 = 0.f, ac10 = 0.f, ac11 = 0.f;

    LOADG(A, 0) SB
    LOADG(B, 1) SB  CONSUMEG(A, 0) SB
    LOADG(A, 2) SB  CONSUMEG(B, 1) SB
    LOADG(B, 3) SB  CONSUMEG(A, 2) SB
    LOADG(A, 4) SB  CONSUMEG(B, 3) SB
    LOADG(B, 5) SB  CONSUMEG(A, 4) SB
    CONSUMEG(B, 5)

    if (hh == 1) {
        partial[0][a] = ac00 + ac01;
        partial[1][a] = ac10 + ac11;
    }
    __syncthreads();

    float logit[PT];
    const int wv = tid >> 6;             // 0/1 for hh==0 threads
    if (hh == 0) {
        const float ps[PT] = { ac00 + ac01, ac10 + ac11 };
        #pragma unroll
        for (int p = 0; p < PT; ++p) {
            logit[p] = swr_s - 2.0f * (ps[p] + partial[p][a]) + maskneg[p][a];
            out_logits[((size_t)(bp0 + p) * Cc + c) * Ss + a] = logit[p];
            float mx = logit[p];
            #pragma unroll
            for (int off = 32; off; off >>= 1) mx = fmaxf(mx, __shfl_xor(mx, off, 64));
            if (lane == 0) redmax[p][wv] = mx;
        }
    }
    __syncthreads();

    if (hh == 0) {
        #pragma unroll
        for (int p = 0; p < PT; ++p) {
            const float rm = fmaxf(redmax[p][0], redmax[p][1]);
            const float e  = __builtin_amdgcn_exp2f((logit[p] - rm) * 1.4426950408889634f);
            const float tg = target[((size_t)(bp0 + p) * Cc + c) * Ss + a];
            float se = e, st = tg, sx = tg * logit[p];
            #pragma unroll
            for (int off = 32; off; off >>= 1) {
                se += __shfl_xor(se, off, 64);
                st += __shfl_xor(st, off, 64);
                sx += __shfl_xor(sx, off, 64);
            }
            if (lane == 0) { red3[p][wv][0] = se; red3[p][wv][1] = st; red3[p][wv][2] = sx; }
        }
    }
    __syncthreads();

    if (tid == 0) {
        float nsum = 0.f, dsum = 0.f;
        #pragma unroll
        for (int p = 0; p < PT; ++p) {
            const float rm = fmaxf(redmax[p][0], redmax[p][1]);
            const float SE = red3[p][0][0] + red3[p][1][0];
            const float ST = red3[p][0][1] + red3[p][1][1];
            const float SX = red3[p][0][2] + red3[p][1][2];
            const float lse = rm + __builtin_amdgcn_logf(SE) * 0.6931471805599453f;
            nsum += lse * ST - SX;
            dsum += ST;
        }
        atomicAdd(&accum[0], nsum);
        atomicAdd(&accum[1], dsum);
        __threadfence();
        const unsigned old = atomicAdd((unsigned*)(accum + 2), 1u);
        if (old == (unsigned)(NBLK - 1)) {          // last block: finalize loss
            const float n = atomicAdd(&accum[0], 0.0f);
            const float d = atomicAdd(&accum[1], 0.0f);
            out_loss[0] = n / d;
        }
    }
}

extern "C" void kernel_launch(void* const* d_in, const int* in_sizes, int n_in,
                              void* d_out, int out_size, void* d_ws, size_t ws_size,
                              hipStream_t stream) {
    const float* seq    = (const float*)d_in[0];
    const int*   att    = (const int*)  d_in[1];
    const int*   ng     = (const int*)  d_in[2];
    const float* target = (const float*)d_in[3];
    const float* Wprd   = (const float*)d_in[4];
    const float* bprd   = (const float*)d_in[5];
    const float* Warg   = (const float*)d_in[6];
    const float* barg   = (const float*)d_in[7];
    const float* Wout   = (const float*)d_in[8];

    float*  out    = (float*)d_out;
    float*  hp_out = (float*)d_ws;                       // 196608 floats
    ushort* haTb   = (ushort*)(hp_out + 196608);         // 983040 ushorts
    float*  accum  = hp_out + 196608 + 491520;           // 3 slots

    gemm_mfma<<<dim3(4, 144), 256, 0, stream>>>(seq, Wprd, Warg, bprd, barg,
                                                hp_out, haTb, accum);
    biaffine_loss<<<dim3(NBLK), 256, 0, stream>>>(hp_out, haTb, Wout, ng, att, target,
                                                  out + 1, accum, out);
}

// Round 13
// 174.050 us; speedup vs baseline: 1.4620x; 1.0009x over previous
//
#include <hip/hip_runtime.h>
#include <math.h>

#define Bb 2
#define Ss 128
#define Hh 768
#define Cc 5
#define Mm 256       // Bb*Ss
#define NEGV -1024.0f
#define SCALE 2.8853900817779268f   // 2/ln(2): stored pre-scaled so exp2(hp'+ha') = e^{2x}

// haTb: bf16 [b][c][h8][a][h&7], h8=h>>3 in [0,96)
// ushort index = ((b*5+c)*96 + h8)*1024 + a*8 + (h&7)
#define PT 2
#define NBLK (Mm / PT * Cc)   // 640

typedef __attribute__((ext_vector_type(8))) short bf16x8;
typedef __attribute__((ext_vector_type(4))) float f32x4;
typedef unsigned short ushort;

__device__ __forceinline__ unsigned pack_hi16(float hi, float lo) {
    return (__float_as_uint(hi) & 0xFFFF0000u) | (__float_as_uint(lo) >> 16);
}
__device__ __forceinline__ bf16x8 pack_bf16x8(float4 lo, float4 hi) {
    union { bf16x8 v; unsigned u[4]; } r;
    r.u[0] = pack_hi16(lo.y, lo.x);
    r.u[1] = pack_hi16(lo.w, lo.z);
    r.u[2] = pack_hi16(hi.y, hi.x);
    r.u[3] = pack_hi16(hi.w, hi.z);
    return r.v;
}

#define SB __builtin_amdgcn_sched_barrier(0);

// ---------------- Kernel 1: K-split bf16 MFMA GEMM -> hp (fp32) + haTb (bf16) ----------------
// Grid (16,36): block = 16 rows x 128 cols. 512 thr = 8 waves = (wn 0..3) x (ws 0..1 K-half).
// Wave: 16x32 tile over its 384-K half, 12 iters, sched_barrier ping-pong (6 loads/group).
// K-halves summed via LDS; ws=0 waves run the epilogue.

#define GLG(R, it) \
    R##a0 = *(const float4*)(arow  + (it)*32);     R##a1 = *(const float4*)(arow  + (it)*32 + 4); \
    R##b0 = *(const float4*)(brow0 + (it)*32);     R##b1 = *(const float4*)(brow0 + (it)*32 + 4); \
    R##b2 = *(const float4*)(brow1 + (it)*32);     R##b3 = *(const float4*)(brow1 + (it)*32 + 4);

#define GCONS(R) { \
    bf16x8 af  = pack_bf16x8(R##a0, R##a1); \
    bf16x8 bf0 = pack_bf16x8(R##b0, R##b1); \
    bf16x8 bf1 = pack_bf16x8(R##b2, R##b3); \
    acc0 = __builtin_amdgcn_mfma_f32_16x16x32_bf16(af, bf0, acc0, 0, 0, 0); \
    acc1 = __builtin_amdgcn_mfma_f32_16x16x32_bf16(af, bf1, acc1, 0, 0, 0); \
}

__global__ __launch_bounds__(512, 4)
void gemm_mfma(const float* __restrict__ X,
               const float* __restrict__ Wprd,
               const float* __restrict__ Warg,
               const float* __restrict__ bprd,
               const float* __restrict__ barg,
               float* __restrict__ hp_out,
               ushort* __restrict__ haTb,
               float* __restrict__ accum)
{
    __shared__ float red[4][16][34];   // [wn][row][col(32)+2 pad]

    if (blockIdx.x == 0 && blockIdx.y == 0 && threadIdx.x == 0) {
        accum[0] = 0.f; accum[1] = 0.f;
        ((unsigned*)accum)[2] = 0u;      // completion counter
    }
    const int bm   = blockIdx.x;          // 0..15 (16 rows)
    const int bn   = blockIdx.y;          // 0..35 (128 cols)
    const int wave = threadIdx.x >> 6;
    const int ws   = wave & 1;            // K-half
    const int wn   = wave >> 1;           // n-pair 0..3
    const int lane = threadIdx.x & 63;
    const int l16  = lane & 15;
    const int quad = lane >> 4;

    const int nb = bn * 128 + wn * 32;    // never straddles hp/ha or c boundary
    const float* Wsrc; const float* bsrc;
    if (nb < Hh) { Wsrc = Wprd + (size_t)nb * Hh;        bsrc = bprd + nb; }
    else         { Wsrc = Warg + (size_t)(nb - Hh) * Hh; bsrc = barg + (nb - Hh); }

    const float* arow  = X    + (size_t)(bm * 16 + l16) * Hh + ws * 384 + quad * 8;
    const float* brow0 = Wsrc + (size_t)l16 * Hh        + ws * 384 + quad * 8;
    const float* brow1 = Wsrc + (size_t)(16 + l16) * Hh + ws * 384 + quad * 8;

    f32x4 acc0 = {0.f, 0.f, 0.f, 0.f};
    f32x4 acc1 = {0.f, 0.f, 0.f, 0.f};

    float4 Pa0, Pa1, Pb0, Pb1, Pb2, Pb3;
    float4 Qa0, Qa1, Qb0, Qb1, Qb2, Qb3;

    GLG(P, 0)  SB
    GLG(Q, 1)  SB  GCONS(P)  SB
    GLG(P, 2)  SB  GCONS(Q)  SB
    GLG(Q, 3)  SB  GCONS(P)  SB
    GLG(P, 4)  SB  GCONS(Q)  SB
    GLG(Q, 5)  SB  GCONS(P)  SB
    GLG(P, 6)  SB  GCONS(Q)  SB
    GLG(Q, 7)  SB  GCONS(P)  SB
    GLG(P, 8)  SB  GCONS(Q)  SB
    GLG(Q, 9)  SB  GCONS(P)  SB
    GLG(P, 10) SB  GCONS(Q)  SB
    GLG(Q, 11) SB  GCONS(P)  SB
    GCONS(Q)

    // K-half reduction through LDS
    if (ws == 1) {
        #pragma unroll
        for (int r = 0; r < 4; ++r) {
            red[wn][quad * 4 + r][l16]      = acc0[r];
            red[wn][quad * 4 + r][16 + l16] = acc1[r];
        }
    }
    __syncthreads();
    if (ws == 1) return;

    const float sb0 = SCALE * bsrc[l16];
    const float sb1 = SCALE * bsrc[16 + l16];

    if (nb < Hh) {   // hp: row-major fp32 [m][h]
        #pragma unroll
        for (int r = 0; r < 4; ++r) {
            const int mm = bm * 16 + quad * 4 + r;
            const float v0 = SCALE * (acc0[r] + red[wn][quad * 4 + r][l16])      + sb0;
            const float v1 = SCALE * (acc1[r] + red[wn][quad * 4 + r][16 + l16]) + sb1;
            hp_out[(size_t)mm * Hh + nb + l16]      = v0;
            hp_out[(size_t)mm * Hh + nb + 16 + l16] = v1;
        }
    } else {         // ha -> haTb bf16 [b][c][h>>3][a][h&7]
        const int q  = nb - Hh;
        const int cU = q / Hh;
        const int h0 = q % Hh;
        const int hA = h0 + l16;
        const int hB = h0 + 16 + l16;
        #pragma unroll
        for (int r = 0; r < 4; ++r) {
            const int mm = bm * 16 + quad * 4 + r;
            const int bI = mm >> 7, aI = mm & 127;
            const size_t base = ((size_t)(bI * Cc + cU) * 96) * 1024 + (size_t)aI * 8;
            const float v0 = SCALE * (acc0[r] + red[wn][quad * 4 + r][l16])      + sb0;
            const float v1 = SCALE * (acc1[r] + red[wn][quad * 4 + r][16 + l16]) + sb1;
            haTb[base + (size_t)(hA >> 3) * 1024 + (hA & 7)] = (ushort)(__float_as_uint(v0) >> 16);
            haTb[base + (size_t)(hB >> 3) * 1024 + (hB & 7)] = (ushort)(__float_as_uint(v1) >> 16);
        }
    }
}

// ---------------- Kernel 2: biaffine, PT=2, bf16 ha stream, sched_barrier ping-pong ----------------
#define LOADG(R, g) \
    R##0 = hap4[((g)*8+0)*128]; R##1 = hap4[((g)*8+1)*128]; \
    R##2 = hap4[((g)*8+2)*128]; R##3 = hap4[((g)*8+3)*128]; \
    R##4 = hap4[((g)*8+4)*128]; R##5 = hap4[((g)*8+5)*128]; \
    R##6 = hap4[((g)*8+6)*128]; R##7 = hap4[((g)*8+7)*128];

#define C1(u, hx) { \
    const float f0 = __uint_as_float((u).x << 16); \
    const float f1 = __uint_as_float((u).x & 0xFFFF0000u); \
    const float f2 = __uint_as_float((u).y << 16); \
    const float f3 = __uint_as_float((u).y & 0xFFFF0000u); \
    const float f4 = __uint_as_float((u).z << 16); \
    const float f5 = __uint_as_float((u).z & 0xFFFF0000u); \
    const float f6 = __uint_as_float((u).w << 16); \
    const float f7 = __uint_as_float((u).w & 0xFFFF0000u); \
    const float4 wA = *(const float4*)(wc_s + (hx)); \
    const float4 wB = *(const float4*)(wc_s + (hx) + 4); \
    const float4 h0A = *(const float4*)(&hp_s[0][hx]); \
    const float4 h0B = *(const float4*)(&hp_s[0][(hx) + 4]); \
    const float4 h1A = *(const float4*)(&hp_s[1][hx]); \
    const float4 h1B = *(const float4*)(&hp_s[1][(hx) + 4]); \
    float r; \
    r = __builtin_amdgcn_rcpf(__builtin_amdgcn_exp2f(h0A.x + f0) + 1.0f); ac00 = fmaf(wA.x, r, ac00); \
    r = __builtin_amdgcn_rcpf(__builtin_amdgcn_exp2f(h0A.y + f1) + 1.0f); ac01 = fmaf(wA.y, r, ac01); \
    r = __builtin_amdgcn_rcpf(__builtin_amdgcn_exp2f(h0A.z + f2) + 1.0f); ac00 = fmaf(wA.z, r, ac00); \
    r = __builtin_amdgcn_rcpf(__builtin_amdgcn_exp2f(h0A.w + f3) + 1.0f); ac01 = fmaf(wA.w, r, ac01); \
    r = __builtin_amdgcn_rcpf(__builtin_amdgcn_exp2f(h0B.x + f4) + 1.0f); ac00 = fmaf(wB.x, r, ac00); \
    r = __builtin_amdgcn_rcpf(__builtin_amdgcn_exp2f(h0B.y + f5) + 1.0f); ac01 = fmaf(wB.y, r, ac01); \
    r = __builtin_amdgcn_rcpf(__builtin_amdgcn_exp2f(h0B.z + f6) + 1.0f); ac00 = fmaf(wB.z, r, ac00); \
    r = __builtin_amdgcn_rcpf(__builtin_amdgcn_exp2f(h0B.w + f7) + 1.0f); ac01 = fmaf(wB.w, r, ac01); \
    r = __builtin_amdgcn_rcpf(__builtin_amdgcn_exp2f(h1A.x + f0) + 1.0f); ac10 = fmaf(wA.x, r, ac10); \
    r = __builtin_amdgcn_rcpf(__builtin_amdgcn_exp2f(h1A.y + f1) + 1.0f); ac11 = fmaf(wA.y, r, ac11); \
    r = __builtin_amdgcn_rcpf(__builtin_amdgcn_exp2f(h1A.z + f2) + 1.0f); ac10 = fmaf(wA.z, r, ac10); \
    r = __builtin_amdgcn_rcpf(__builtin_amdgcn_exp2f(h1A.w + f3) + 1.0f); ac11 = fmaf(wA.w, r, ac11); \
    r = __builtin_amdgcn_rcpf(__builtin_amdgcn_exp2f(h1B.x + f4) + 1.0f); ac10 = fmaf(wB.x, r, ac10); \
    r = __builtin_amdgcn_rcpf(__builtin_amdgcn_exp2f(h1B.y + f5) + 1.0f); ac11 = fmaf(wB.y, r, ac11); \
    r = __builtin_amdgcn_rcpf(__builtin_amdgcn_exp2f(h1B.z + f6) + 1.0f); ac10 = fmaf(wB.z, r, ac10); \
    r = __builtin_amdgcn_rcpf(__builtin_amdgcn_exp2f(h1B.w + f7) + 1.0f); ac11 = fmaf(wB.w, r, ac11); \
}

#define CONSUMEG(R, g) \
    C1(R##0, hbase + ((g)*8+0)*8)  C1(R##1, hbase + ((g)*8+1)*8) \
    C1(R##2, hbase + ((g)*8+2)*8)  C1(R##3, hbase + ((g)*8+3)*8) \
    C1(R##4, hbase + ((g)*8+4)*8)  C1(R##5, hbase + ((g)*8+5)*8) \
    C1(R##6, hbase + ((g)*8+6)*8)  C1(R##7, hbase + ((g)*8+7)*8)

__global__ __launch_bounds__(256, 4)
void biaffine_loss(const float* __restrict__ hp_all,
                   const ushort* __restrict__ haTb,
                   const float* __restrict__ Wout,
                   const int* __restrict__ ng,
                   const int* __restrict__ att,
                   const float* __restrict__ target,
                   float* __restrict__ out_logits,
                   float* __restrict__ accum,
                   float* __restrict__ out_loss)
{
    __shared__ float hp_s[PT][Hh];
    __shared__ float wc_s[Hh];
    __shared__ float partial[PT][Ss];
    __shared__ float maskneg[PT][Ss];
    __shared__ float redmax[PT][2];
    __shared__ float red3[PT][2][3];
    __shared__ float swr_s;

    const int pt  = blockIdx.x / Cc;     // 0..127
    const int c   = blockIdx.x - pt * Cc;
    const int bp0 = pt * PT;
    const int b   = bp0 >> 7;
    const int tid = threadIdx.x;
    const int a   = tid & (Ss - 1);
    const int hh  = tid >> 7;            // 0/1: h-half (waves 0,1 -> 0; 2,3 -> 1)
    const int lane = tid & 63;

    // stage hp rows + wc row into LDS (coalesced); mask
    for (int i = tid; i < PT * Hh; i += 256) ((float*)hp_s)[i] = hp_all[(size_t)bp0 * Hh + i];
    for (int i = tid; i < Hh; i += 256)      wc_s[i] = Wout[(size_t)c * Hh + i];
    {
        const int p_i = tid >> 7;
        const int aa  = tid & (Ss - 1);
        int any = 0;
        if (att[b * Ss + aa] > 0) {
            const int* ngp = ng + (size_t)(bp0 + p_i) * Cc * Ss + aa;
            #pragma unroll
            for (int cc = 0; cc < Cc; ++cc) any |= ngp[cc * Ss];
        }
        maskneg[p_i][aa] = any ? 0.0f : NEGV;
    }
    __syncthreads();

    if (tid < 64) {    // wave 0: sumW[c]
        float s = 0.f;
        #pragma unroll
        for (int i = 0; i < Hh / 64; ++i) s += wc_s[tid + i * 64];
        #pragma unroll
        for (int off = 32; off; off >>= 1) s += __shfl_xor(s, off, 64);
        if (tid == 0) swr_s = s;
    }

    // thread's ha stream: uint4 j = 8 h values; index = (hh*48 + j)*128 + a
    const uint4* hap4 = (const uint4*)(haTb + ((size_t)(b * Cc + c) * 96) * 1024)
                      + (size_t)hh * 48 * 128 + a;
    const int hbase = hh * 384;

    uint4 A0, A1, A2, A3, A4, A5, A6, A7;
    uint4 B0, B1, B2, B3, B4, B5, B6, B7;
    float ac00 = 0.f, ac01 = 0.f, ac10 = 0.f, ac11 = 0.f;

    LOADG(A, 0) SB
    LOADG(B, 1) SB  CONSUMEG(A, 0) SB
    LOADG(A, 2) SB  CONSUMEG(B, 1) SB
    LOADG(B, 3) SB  CONSUMEG(A, 2) SB
    LOADG(A, 4) SB  CONSUMEG(B, 3) SB
    LOADG(B, 5) SB  CONSUMEG(A, 4) SB
    CONSUMEG(B, 5)

    if (hh == 1) {
        partial[0][a] = ac00 + ac01;
        partial[1][a] = ac10 + ac11;
    }
    __syncthreads();

    float logit[PT];
    const int wv = tid >> 6;             // 0/1 for hh==0 threads
    if (hh == 0) {
        const float ps[PT] = { ac00 + ac01, ac10 + ac11 };
        #pragma unroll
        for (int p = 0; p < PT; ++p) {
            logit[p] = swr_s - 2.0f * (ps[p] + partial[p][a]) + maskneg[p][a];
            out_logits[((size_t)(bp0 + p) * Cc + c) * Ss + a] = logit[p];
            float mx = logit[p];
            #pragma unroll
            for (int off = 32; off; off >>= 1) mx = fmaxf(mx, __shfl_xor(mx, off, 64));
            if (lane == 0) redmax[p][wv] = mx;
        }
    }
    __syncthreads();

    if (hh == 0) {
        #pragma unroll
        for (int p = 0; p < PT; ++p) {
            const float rm = fmaxf(redmax[p][0], redmax[p][1]);
            const float e  = __builtin_amdgcn_exp2f((logit[p] - rm) * 1.4426950408889634f);
            const float tg = target[((size_t)(bp0 + p) * Cc + c) * Ss + a];
            float se = e, st = tg, sx = tg * logit[p];
            #pragma unroll
            for (int off = 32; off; off >>= 1) {
                se += __shfl_xor(se, off, 64);
                st += __shfl_xor(st, off, 64);
                sx += __shfl_xor(sx, off, 64);
            }
            if (lane == 0) { red3[p][wv][0] = se; red3[p][wv][1] = st; red3[p][wv][2] = sx; }
        }
    }
    __syncthreads();

    if (tid == 0) {
        float nsum = 0.f, dsum = 0.f;
        #pragma unroll
        for (int p = 0; p < PT; ++p) {
            const float rm = fmaxf(redmax[p][0], redmax[p][1]);
            const float SE = red3[p][0][0] + red3[p][1][0];
            const float ST = red3[p][0][1] + red3[p][1][1];
            const float SX = red3[p][0][2] + red3[p][1][2];
            const float lse = rm + __builtin_amdgcn_logf(SE) * 0.6931471805599453f;
            nsum += lse * ST - SX;
            dsum += ST;
        }
        atomicAdd(&accum[0], nsum);
        atomicAdd(&accum[1], dsum);
        __threadfence();
        const unsigned old = atomicAdd((unsigned*)(accum + 2), 1u);
        if (old == (unsigned)(NBLK - 1)) {          // last block: finalize loss
            const float n = atomicAdd(&accum[0], 0.0f);
            const float d = atomicAdd(&accum[1], 0.0f);
            out_loss[0] = n / d;
        }
    }
}

extern "C" void kernel_launch(void* const* d_in, const int* in_sizes, int n_in,
                              void* d_out, int out_size, void* d_ws, size_t ws_size,
                              hipStream_t stream) {
    const float* seq    = (const float*)d_in[0];
    const int*   att    = (const int*)  d_in[1];
    const int*   ng     = (const int*)  d_in[2];
    const float* target = (const float*)d_in[3];
    const float* Wprd   = (const float*)d_in[4];
    const float* bprd   = (const float*)d_in[5];
    const float* Warg   = (const float*)d_in[6];
    const float* barg   = (const float*)d_in[7];
    const float* Wout   = (const float*)d_in[8];

    float*  out    = (float*)d_out;
    float*  hp_out = (float*)d_ws;                       // 196608 floats
    ushort* haTb   = (ushort*)(hp_out + 196608);         // 983040 ushorts
    float*  accum  = hp_out + 196608 + 491520;           // 3 slots

    gemm_mfma<<<dim3(16, 36), 512, 0, stream>>>(seq, Wprd, Warg, bprd, barg,
                                                hp_out, haTb, accum);
    biaffine_loss<<<dim3(NBLK), 256, 0, stream>>>(hp_out, haTb, Wout, ng, att, target,
                                                  out + 1, accum, out);
}

// Round 14
// 141.068 us; speedup vs baseline: 1.8038x; 1.2338x over previous
//
#include <hip/hip_runtime.h>
#include <math.h>

#define Bb 2
#define Ss 128
#define Hh 768
#define Cc 5
#define Mm 256       // Bb*Ss
#define NEGV -1024.0f
#define SCALE 2.8853900817779268f   // 2/ln(2): stored pre-scaled so exp2(hp'+ha') = e^{2x}

// haTb: bf16 [b][c][h8][a][h&7], h8=h>>3 in [0,96)
// ushort index = ((b*5+c)*96 + h8)*1024 + a*8 + (h&7)
#define PT 2
#define NBLK (Mm / PT * Cc)   // 640

typedef __attribute__((ext_vector_type(8))) short bf16x8;
typedef __attribute__((ext_vector_type(4))) float f32x4;
typedef unsigned short ushort;

__device__ __forceinline__ unsigned pack_hi16(float hi, float lo) {
    return (__float_as_uint(hi) & 0xFFFF0000u) | (__float_as_uint(lo) >> 16);
}
__device__ __forceinline__ bf16x8 pack_bf16x8(float4 lo, float4 hi) {
    union { bf16x8 v; unsigned u[4]; } r;
    r.u[0] = pack_hi16(lo.y, lo.x);
    r.u[1] = pack_hi16(lo.w, lo.z);
    r.u[2] = pack_hi16(hi.y, hi.x);
    r.u[3] = pack_hi16(hi.w, hi.z);
    return r.v;
}

#define SB __builtin_amdgcn_sched_barrier(0);

// ---------------- Kernel 1: LDS-staged bf16 MFMA GEMM -> hp (fp32) + haTb (bf16) ----------------
// Grid (4,72): block tile 64 rows x 64 cols, 256 thr = 4 waves, each wave 32x32 (2x2 MFMA tiles).
// Per BK=32: coalesced global fp32 loads -> pack bf16 -> LDS; fragments via 1 ds_read_b128 each.
__global__ __launch_bounds__(256)
void gemm_mfma(const float* __restrict__ X,
               const float* __restrict__ Wprd,
               const float* __restrict__ Warg,
               const float* __restrict__ bprd,
               const float* __restrict__ barg,
               float* __restrict__ hp_out,
               ushort* __restrict__ haTb,
               float* __restrict__ accum)
{
    __shared__ __align__(16) ushort Asb[64][40];   // bf16 A-chunk, row stride 40 (16B-aligned, de-conflicted)
    __shared__ __align__(16) ushort Bsb[64][40];

    if (blockIdx.x == 0 && blockIdx.y == 0 && threadIdx.x == 0) {
        accum[0] = 0.f; accum[1] = 0.f;
        ((unsigned*)accum)[2] = 0u;      // completion counter
    }
    const int bm   = blockIdx.x;          // 0..3  (64 rows)
    const int bn   = blockIdx.y;          // 0..71 (64 cols)
    const int tid  = threadIdx.x;
    const int wave = tid >> 6;
    const int lane = tid & 63;
    const int l16  = lane & 15;
    const int quad = lane >> 4;
    const int wm   = wave & 1;            // m-half of block tile
    const int wn2  = wave >> 1;           // n-half

    const float* Wsrc; const float* bsrc;
    const int nb = bn * 64;
    if (nb < Hh) { Wsrc = Wprd + (size_t)nb * Hh;        bsrc = bprd + nb; }
    else         { Wsrc = Warg + (size_t)(nb - Hh) * Hh; bsrc = barg + (nb - Hh); }

    // staging map: thread t -> row = t>>2 (0..63), ko = (t&3)*8  (8 consecutive k)
    const int srow = tid >> 2;
    const int sko  = (tid & 3) * 8;
    const float* gA = X    + (size_t)(bm * 64 + srow) * Hh + sko;
    const float* gB = Wsrc + (size_t)srow * Hh + sko;

    float4 pa0 = *(const float4*)(gA);
    float4 pa1 = *(const float4*)(gA + 4);
    float4 pb0 = *(const float4*)(gB);
    float4 pb1 = *(const float4*)(gB + 4);

    f32x4 acc00 = {0.f,0.f,0.f,0.f}, acc01 = {0.f,0.f,0.f,0.f};
    f32x4 acc10 = {0.f,0.f,0.f,0.f}, acc11 = {0.f,0.f,0.f,0.f};

    const int arow0 = wm * 32 + l16;       // fragment rows in block tile
    const int brow0 = wn2 * 32 + l16;

    for (int k0 = 0; k0 < Hh; k0 += 32) {
        *(bf16x8*)&Asb[srow][sko] = pack_bf16x8(pa0, pa1);
        *(bf16x8*)&Bsb[srow][sko] = pack_bf16x8(pb0, pb1);
        __syncthreads();
        const int kn = k0 + 32;
        if (kn < Hh) {                      // prefetch next chunk during compute
            pa0 = *(const float4*)(gA + kn);
            pa1 = *(const float4*)(gA + kn + 4);
            pb0 = *(const float4*)(gB + kn);
            pb1 = *(const float4*)(gB + kn + 4);
        }
        bf16x8 a0 = *(const bf16x8*)&Asb[arow0][quad * 8];
        bf16x8 a1 = *(const bf16x8*)&Asb[arow0 + 16][quad * 8];
        bf16x8 b0 = *(const bf16x8*)&Bsb[brow0][quad * 8];
        bf16x8 b1 = *(const bf16x8*)&Bsb[brow0 + 16][quad * 8];
        acc00 = __builtin_amdgcn_mfma_f32_16x16x32_bf16(a0, b0, acc00, 0, 0, 0);
        acc01 = __builtin_amdgcn_mfma_f32_16x16x32_bf16(a0, b1, acc01, 0, 0, 0);
        acc10 = __builtin_amdgcn_mfma_f32_16x16x32_bf16(a1, b0, acc10, 0, 0, 0);
        acc11 = __builtin_amdgcn_mfma_f32_16x16x32_bf16(a1, b1, acc11, 0, 0, 0);
        __syncthreads();
    }

    // epilogue: D[m = quad*4+r][n = l16] per tile
    const float sb0 = SCALE * bsrc[wn2 * 32 + l16];
    const float sb1 = SCALE * bsrc[wn2 * 32 + 16 + l16];
    const int mrow = bm * 64 + wm * 32 + quad * 4;

    if (nb < Hh) {   // hp: row-major fp32 [m][h]
        const int nc0 = nb + wn2 * 32 + l16;
        #pragma unroll
        for (int r = 0; r < 4; ++r) {
            hp_out[(size_t)(mrow + r) * Hh + nc0]          = SCALE * acc00[r] + sb0;
            hp_out[(size_t)(mrow + r) * Hh + nc0 + 16]     = SCALE * acc01[r] + sb1;
            hp_out[(size_t)(mrow + r + 16) * Hh + nc0]     = SCALE * acc10[r] + sb0;
            hp_out[(size_t)(mrow + r + 16) * Hh + nc0 + 16] = SCALE * acc11[r] + sb1;
        }
    } else {         // ha -> haTb bf16 [b][c][h>>3][a][h&7]
        const int q   = nb - Hh;
        const int cU  = q / Hh;
        const int hA  = (q % Hh) + wn2 * 32 + l16;       // n-tile 0 col
        const int hB  = hA + 16;                          // n-tile 1 col
        const size_t offA = (size_t)(hA >> 3) * 1024 + (hA & 7);
        const size_t offB = (size_t)(hB >> 3) * 1024 + (hB & 7);
        #pragma unroll
        for (int r = 0; r < 4; ++r) {
            #pragma unroll
            for (int mh = 0; mh < 2; ++mh) {
                const int mm = mrow + r + mh * 16;
                const int bI = mm >> 7, aI = mm & 127;
                const size_t base = ((size_t)(bI * Cc + cU) * 96) * 1024 + (size_t)aI * 8;
                const float v0 = SCALE * (mh ? acc10[r] : acc00[r]) + sb0;
                const float v1 = SCALE * (mh ? acc11[r] : acc01[r]) + sb1;
                haTb[base + offA] = (ushort)(__float_as_uint(v0) >> 16);
                haTb[base + offB] = (ushort)(__float_as_uint(v1) >> 16);
            }
        }
    }
}

// ---------------- Kernel 2: biaffine, PT=2, bf16 ha stream, sched_barrier ping-pong ----------------
#define LOADG(R, g) \
    R##0 = hap4[((g)*8+0)*128]; R##1 = hap4[((g)*8+1)*128]; \
    R##2 = hap4[((g)*8+2)*128]; R##3 = hap4[((g)*8+3)*128]; \
    R##4 = hap4[((g)*8+4)*128]; R##5 = hap4[((g)*8+5)*128]; \
    R##6 = hap4[((g)*8+6)*128]; R##7 = hap4[((g)*8+7)*128];

#define C1(u, hx) { \
    const float f0 = __uint_as_float((u).x << 16); \
    const float f1 = __uint_as_float((u).x & 0xFFFF0000u); \
    const float f2 = __uint_as_float((u).y << 16); \
    const float f3 = __uint_as_float((u).y & 0xFFFF0000u); \
    const float f4 = __uint_as_float((u).z << 16); \
    const float f5 = __uint_as_float((u).z & 0xFFFF0000u); \
    const float f6 = __uint_as_float((u).w << 16); \
    const float f7 = __uint_as_float((u).w & 0xFFFF0000u); \
    const float4 wA = *(const float4*)(wc_s + (hx)); \
    const float4 wB = *(const float4*)(wc_s + (hx) + 4); \
    const float4 h0A = *(const float4*)(&hp_s[0][hx]); \
    const float4 h0B = *(const float4*)(&hp_s[0][(hx) + 4]); \
    const float4 h1A = *(const float4*)(&hp_s[1][hx]); \
    const float4 h1B = *(const float4*)(&hp_s[1][(hx) + 4]); \
    float r; \
    r = __builtin_amdgcn_rcpf(__builtin_amdgcn_exp2f(h0A.x + f0) + 1.0f); ac00 = fmaf(wA.x, r, ac00); \
    r = __builtin_amdgcn_rcpf(__builtin_amdgcn_exp2f(h0A.y + f1) + 1.0f); ac01 = fmaf(wA.y, r, ac01); \
    r = __builtin_amdgcn_rcpf(__builtin_amdgcn_exp2f(h0A.z + f2) + 1.0f); ac00 = fmaf(wA.z, r, ac00); \
    r = __builtin_amdgcn_rcpf(__builtin_amdgcn_exp2f(h0A.w + f3) + 1.0f); ac01 = fmaf(wA.w, r, ac01); \
    r = __builtin_amdgcn_rcpf(__builtin_amdgcn_exp2f(h0B.x + f4) + 1.0f); ac00 = fmaf(wB.x, r, ac00); \
    r = __builtin_amdgcn_rcpf(__builtin_amdgcn_exp2f(h0B.y + f5) + 1.0f); ac01 = fmaf(wB.y, r, ac01); \
    r = __builtin_amdgcn_rcpf(__builtin_amdgcn_exp2f(h0B.z + f6) + 1.0f); ac00 = fmaf(wB.z, r, ac00); \
    r = __builtin_amdgcn_rcpf(__builtin_amdgcn_exp2f(h0B.w + f7) + 1.0f); ac01 = fmaf(wB.w, r, ac01); \
    r = __builtin_amdgcn_rcpf(__builtin_amdgcn_exp2f(h1A.x + f0) + 1.0f); ac10 = fmaf(wA.x, r, ac10); \
    r = __builtin_amdgcn_rcpf(__builtin_amdgcn_exp2f(h1A.y + f1) + 1.0f); ac11 = fmaf(wA.y, r, ac11); \
    r = __builtin_amdgcn_rcpf(__builtin_amdgcn_exp2f(h1A.z + f2) + 1.0f); ac10 = fmaf(wA.z, r, ac10); \
    r = __builtin_amdgcn_rcpf(__builtin_amdgcn_exp2f(h1A.w + f3) + 1.0f); ac11 = fmaf(wA.w, r, ac11); \
    r = __builtin_amdgcn_rcpf(__builtin_amdgcn_exp2f(h1B.x + f4) + 1.0f); ac10 = fmaf(wB.x, r, ac10); \
    r = __builtin_amdgcn_rcpf(__builtin_amdgcn_exp2f(h1B.y + f5) + 1.0f); ac11 = fmaf(wB.y, r, ac11); \
    r = __builtin_amdgcn_rcpf(__builtin_amdgcn_exp2f(h1B.z + f6) + 1.0f); ac10 = fmaf(wB.z, r, ac10); \
    r = __builtin_amdgcn_rcpf(__builtin_amdgcn_exp2f(h1B.w + f7) + 1.0f); ac11 = fmaf(wB.w, r, ac11); \
}

#define CONSUMEG(R, g) \
    C1(R##0, hbase + ((g)*8+0)*8)  C1(R##1, hbase + ((g)*8+1)*8) \
    C1(R##2, hbase + ((g)*8+2)*8)  C1(R##3, hbase + ((g)*8+3)*8) \
    C1(R##4, hbase + ((g)*8+4)*8)  C1(R##5, hbase + ((g)*8+5)*8) \
    C1(R##6, hbase + ((g)*8+6)*8)  C1(R##7, hbase + ((g)*8+7)*8)

__global__ __launch_bounds__(256, 4)
void biaffine_loss(const float* __restrict__ hp_all,
                   const ushort* __restrict__ haTb,
                   const float* __restrict__ Wout,
                   const int* __restrict__ ng,
                   const int* __restrict__ att,
                   const float* __restrict__ target,
                   float* __restrict__ out_logits,
                   float* __restrict__ accum,
                   float* __restrict__ out_loss)
{
    __shared__ float hp_s[PT][Hh];
    __shared__ float wc_s[Hh];
    __shared__ float partial[PT][Ss];
    __shared__ float maskneg[PT][Ss];
    __shared__ float redmax[PT][2];
    __shared__ float red3[PT][2][3];
    __shared__ float swr_s;

    const int pt  = blockIdx.x / Cc;     // 0..127
    const int c   = blockIdx.x - pt * Cc;
    const int bp0 = pt * PT;
    const int b   = bp0 >> 7;
    const int tid = threadIdx.x;
    const int a   = tid & (Ss - 1);
    const int hh  = tid >> 7;            // 0/1: h-half (waves 0,1 -> 0; 2,3 -> 1)
    const int lane = tid & 63;

    // stage hp rows + wc row into LDS (coalesced); mask
    for (int i = tid; i < PT * Hh; i += 256) ((float*)hp_s)[i] = hp_all[(size_t)bp0 * Hh + i];
    for (int i = tid; i < Hh; i += 256)      wc_s[i] = Wout[(size_t)c * Hh + i];
    {
        const int p_i = tid >> 7;
        const int aa  = tid & (Ss - 1);
        int any = 0;
        if (att[b * Ss + aa] > 0) {
            const int* ngp = ng + (size_t)(bp0 + p_i) * Cc * Ss + aa;
            #pragma unroll
            for (int cc = 0; cc < Cc; ++cc) any |= ngp[cc * Ss];
        }
        maskneg[p_i][aa] = any ? 0.0f : NEGV;
    }
    __syncthreads();

    if (tid < 64) {    // wave 0: sumW[c]
        float s = 0.f;
        #pragma unroll
        for (int i = 0; i < Hh / 64; ++i) s += wc_s[tid + i * 64];
        #pragma unroll
        for (int off = 32; off; off >>= 1) s += __shfl_xor(s, off, 64);
        if (tid == 0) swr_s = s;
    }

    // thread's ha stream: uint4 j = 8 h values; index = (hh*48 + j)*128 + a
    const uint4* hap4 = (const uint4*)(haTb + ((size_t)(b * Cc + c) * 96) * 1024)
                      + (size_t)hh * 48 * 128 + a;
    const int hbase = hh * 384;

    uint4 A0, A1, A2, A3, A4, A5, A6, A7;
    uint4 B0, B1, B2, B3, B4, B5, B6, B7;
    float ac00 = 0.f, ac01 = 0.f, ac10 = 0.f, ac11 = 0.f;

    LOADG(A, 0) SB
    LOADG(B, 1) SB  CONSUMEG(A, 0) SB
    LOADG(A, 2) SB  CONSUMEG(B, 1) SB
    LOADG(B, 3) SB  CONSUMEG(A, 2) SB
    LOADG(A, 4) SB  CONSUMEG(B, 3) SB
    LOADG(B, 5) SB  CONSUMEG(A, 4) SB
    CONSUMEG(B, 5)

    if (hh == 1) {
        partial[0][a] = ac00 + ac01;
        partial[1][a] = ac10 + ac11;
    }
    __syncthreads();

    float logit[PT];
    const int wv = tid >> 6;             // 0/1 for hh==0 threads
    if (hh == 0) {
        const float ps[PT] = { ac00 + ac01, ac10 + ac11 };
        #pragma unroll
        for (int p = 0; p < PT; ++p) {
            logit[p] = swr_s - 2.0f * (ps[p] + partial[p][a]) + maskneg[p][a];
            out_logits[((size_t)(bp0 + p) * Cc + c) * Ss + a] = logit[p];
            float mx = logit[p];
            #pragma unroll
            for (int off = 32; off; off >>= 1) mx = fmaxf(mx, __shfl_xor(mx, off, 64));
            if (lane == 0) redmax[p][wv] = mx;
        }
    }
    __syncthreads();

    if (hh == 0) {
        #pragma unroll
        for (int p = 0; p < PT; ++p) {
            const float rm = fmaxf(redmax[p][0], redmax[p][1]);
            const float e  = __builtin_amdgcn_exp2f((logit[p] - rm) * 1.4426950408889634f);
            const float tg = target[((size_t)(bp0 + p) * Cc + c) * Ss + a];
            float se = e, st = tg, sx = tg * logit[p];
            #pragma unroll
            for (int off = 32; off; off >>= 1) {
                se += __shfl_xor(se, off, 64);
                st += __shfl_xor(st, off, 64);
                sx += __shfl_xor(sx, off, 64);
            }
            if (lane == 0) { red3[p][wv][0] = se; red3[p][wv][1] = st; red3[p][wv][2] = sx; }
        }
    }
    __syncthreads();

    if (tid == 0) {
        float nsum = 0.f, dsum = 0.f;
        #pragma unroll
        for (int p = 0; p < PT; ++p) {
            const float rm = fmaxf(redmax[p][0], redmax[p][1]);
            const float SE = red3[p][0][0] + red3[p][1][0];
            const float ST = red3[p][0][1] + red3[p][1][1];
            const float SX = red3[p][0][2] + red3[p][1][2];
            const float lse = rm + __builtin_amdgcn_logf(SE) * 0.6931471805599453f;
            nsum += lse * ST - SX;
            dsum += ST;
        }
        atomicAdd(&accum[0], nsum);
        atomicAdd(&accum[1], dsum);
        __threadfence();
        const unsigned old = atomicAdd((unsigned*)(accum + 2), 1u);
        if (old == (unsigned)(NBLK - 1)) {          // last block: finalize loss
            const float n = atomicAdd(&accum[0], 0.0f);
            const float d = atomicAdd(&accum[1], 0.0f);
            out_loss[0] = n / d;
        }
    }
}

extern "C" void kernel_launch(void* const* d_in, const int* in_sizes, int n_in,
                              void* d_out, int out_size, void* d_ws, size_t ws_size,
                              hipStream_t stream) {
    const float* seq    = (const float*)d_in[0];
    const int*   att    = (const int*)  d_in[1];
    const int*   ng     = (const int*)  d_in[2];
    const float* target = (const float*)d_in[3];
    const float* Wprd   = (const float*)d_in[4];
    const float* bprd   = (const float*)d_in[5];
    const float* Warg   = (const float*)d_in[6];
    const float* barg   = (const float*)d_in[7];
    const float* Wout   = (const float*)d_in[8];

    float*  out    = (float*)d_out;
    float*  hp_out = (float*)d_ws;                       // 196608 floats
    ushort* haTb   = (ushort*)(hp_out + 196608);         // 983040 ushorts
    float*  accum  = hp_out + 196608 + 491520;           // 3 slots

    gemm_mfma<<<dim3(4, 72), 256, 0, stream>>>(seq, Wprd, Warg, bprd, barg,
                                               hp_out, haTb, accum);
    biaffine_loss<<<dim3(NBLK), 256, 0, stream>>>(hp_out, haTb, Wout, ng, att, target,
                                                  out + 1, accum, out);
}

// Round 15
// 137.548 us; speedup vs baseline: 1.8500x; 1.0256x over previous
//
#include <hip/hip_runtime.h>
#include <math.h>

#define Bb 2
#define Ss 128
#define Hh 768
#define Cc 5
#define Mm 256       // Bb*Ss
#define NEGV -1024.0f
#define SCALE 2.8853900817779268f   // 2/ln(2): stored pre-scaled so exp2(hp'+ha') = e^{2x}

// haTb: bf16 [b][c][h8][a][h&7], h8=h>>3 in [0,96)
// ushort index = ((b*5+c)*96 + h8)*1024 + a*8 + (h&7)
#define PT 2
#define NBLK (Mm / PT * Cc)   // 640

typedef __attribute__((ext_vector_type(8))) short bf16x8;
typedef __attribute__((ext_vector_type(4))) float f32x4;
typedef unsigned short ushort;

__device__ __forceinline__ unsigned pack_hi16(float hi, float lo) {
    return (__float_as_uint(hi) & 0xFFFF0000u) | (__float_as_uint(lo) >> 16);
}
__device__ __forceinline__ bf16x8 pack_bf16x8(float4 lo, float4 hi) {
    union { bf16x8 v; unsigned u[4]; } r;
    r.u[0] = pack_hi16(lo.y, lo.x);
    r.u[1] = pack_hi16(lo.w, lo.z);
    r.u[2] = pack_hi16(hi.y, hi.x);
    r.u[3] = pack_hi16(hi.w, hi.z);
    return r.v;
}

#define SB __builtin_amdgcn_sched_barrier(0);

// ---------------- Kernel 1: LDS-staged bf16 MFMA GEMM, 64x32 tiles ----------------
// Grid (4,144) = 576 blocks (2.25/CU). 256 thr = 4 waves; wave = 16-row strip x 32 cols.
__global__ __launch_bounds__(256)
void gemm_mfma(const float* __restrict__ X,
               const float* __restrict__ Wprd,
               const float* __restrict__ Warg,
               const float* __restrict__ bprd,
               const float* __restrict__ barg,
               float* __restrict__ hp_out,
               ushort* __restrict__ haTb,
               float* __restrict__ accum)
{
    __shared__ __align__(16) ushort Asb[64][40];
    __shared__ __align__(16) ushort Bsb[32][40];

    if (blockIdx.x == 0 && blockIdx.y == 0 && threadIdx.x == 0) {
        accum[0] = 0.f; accum[1] = 0.f;
        ((unsigned*)accum)[2] = 0u;      // completion counter
    }
    const int bm   = blockIdx.x;          // 0..3   (64 rows)
    const int bn   = blockIdx.y;          // 0..143 (32 cols)
    const int tid  = threadIdx.x;
    const int wave = tid >> 6;
    const int lane = tid & 63;
    const int l16  = lane & 15;
    const int quad = lane >> 4;

    const float* Wsrc; const float* bsrc;
    const int nb = bn * 32;
    if (nb < Hh) { Wsrc = Wprd + (size_t)nb * Hh;        bsrc = bprd + nb; }
    else         { Wsrc = Warg + (size_t)(nb - Hh) * Hh; bsrc = barg + (nb - Hh); }

    // staging map: A: thread t -> row t>>2 (0..63), ko (t&3)*8; B: threads 0..127 -> rows 0..31
    const int srow = tid >> 2;
    const int sko  = (tid & 3) * 8;
    const float* gA = X + (size_t)(bm * 64 + srow) * Hh + sko;
    const float* gB = Wsrc + (size_t)(tid >> 2) * Hh + sko;   // valid for tid<128

    float4 pa0 = *(const float4*)(gA);
    float4 pa1 = *(const float4*)(gA + 4);
    float4 pb0, pb1;
    if (tid < 128) { pb0 = *(const float4*)(gB); pb1 = *(const float4*)(gB + 4); }

    f32x4 acc0 = {0.f,0.f,0.f,0.f}, acc1 = {0.f,0.f,0.f,0.f};

    for (int k0 = 0; k0 < Hh; k0 += 32) {
        *(bf16x8*)&Asb[srow][sko] = pack_bf16x8(pa0, pa1);
        if (tid < 128) *(bf16x8*)&Bsb[tid >> 2][sko] = pack_bf16x8(pb0, pb1);
        __syncthreads();
        const int kn = k0 + 32;
        if (kn < Hh) {
            pa0 = *(const float4*)(gA + kn);
            pa1 = *(const float4*)(gA + kn + 4);
            if (tid < 128) { pb0 = *(const float4*)(gB + kn); pb1 = *(const float4*)(gB + kn + 4); }
        }
        bf16x8 af = *(const bf16x8*)&Asb[wave * 16 + l16][quad * 8];
        bf16x8 b0 = *(const bf16x8*)&Bsb[l16][quad * 8];
        bf16x8 b1 = *(const bf16x8*)&Bsb[16 + l16][quad * 8];
        acc0 = __builtin_amdgcn_mfma_f32_16x16x32_bf16(af, b0, acc0, 0, 0, 0);
        acc1 = __builtin_amdgcn_mfma_f32_16x16x32_bf16(af, b1, acc1, 0, 0, 0);
        __syncthreads();
    }

    const float sb0 = SCALE * bsrc[l16];
    const float sb1 = SCALE * bsrc[16 + l16];
    const int row = bm * 64 + wave * 16 + quad * 4;

    if (nb < Hh) {   // hp: row-major fp32 [m][h]
        #pragma unroll
        for (int r = 0; r < 4; ++r) {
            const int mm = row + r;
            hp_out[(size_t)mm * Hh + nb + l16]      = SCALE * acc0[r] + sb0;
            hp_out[(size_t)mm * Hh + nb + 16 + l16] = SCALE * acc1[r] + sb1;
        }
    } else {         // ha -> haTb bf16 [b][c][h>>3][a][h&7]
        const int q  = nb - Hh;
        const int cU = q / Hh;
        const int h0 = q % Hh;
        const int hA = h0 + l16;
        const int hB = h0 + 16 + l16;
        const size_t offA = (size_t)(hA >> 3) * 1024 + (hA & 7);
        const size_t offB = (size_t)(hB >> 3) * 1024 + (hB & 7);
        #pragma unroll
        for (int r = 0; r < 4; ++r) {
            const int mm = row + r;
            const int bI = mm >> 7, aI = mm & 127;
            const size_t base = ((size_t)(bI * Cc + cU) * 96) * 1024 + (size_t)aI * 8;
            const float v0 = SCALE * acc0[r] + sb0;
            const float v1 = SCALE * acc1[r] + sb1;
            haTb[base + offA] = (ushort)(__float_as_uint(v0) >> 16);
            haTb[base + offB] = (ushort)(__float_as_uint(v1) >> 16);
        }
    }
}

// ---------------- Kernel 2: biaffine, 512 thr (h-quarters), PT=2, bf16 stream ----------------
// Grid 640 = (p-tile, c). tid = hq*128 + a, hq in 0..3; thread streams 24 uint4 (192 h)
// for PT=2 p-rows. Ping-pong groups of 4 (8 loads in flight). In-block 4-way h-reduction.
#define LOADG4(R, g) \
    R##0 = hap4[((g)*4+0)*128]; R##1 = hap4[((g)*4+1)*128]; \
    R##2 = hap4[((g)*4+2)*128]; R##3 = hap4[((g)*4+3)*128];

#define C1(u, hx) { \
    const float f0 = __uint_as_float((u).x << 16); \
    const float f1 = __uint_as_float((u).x & 0xFFFF0000u); \
    const float f2 = __uint_as_float((u).y << 16); \
    const float f3 = __uint_as_float((u).y & 0xFFFF0000u); \
    const float f4 = __uint_as_float((u).z << 16); \
    const float f5 = __uint_as_float((u).z & 0xFFFF0000u); \
    const float f6 = __uint_as_float((u).w << 16); \
    const float f7 = __uint_as_float((u).w & 0xFFFF0000u); \
    const float4 wA = *(const float4*)(wc_s + (hx)); \
    const float4 wB = *(const float4*)(wc_s + (hx) + 4); \
    const float4 h0A = *(const float4*)(&hp_s[0][hx]); \
    const float4 h0B = *(const float4*)(&hp_s[0][(hx) + 4]); \
    const float4 h1A = *(const float4*)(&hp_s[1][hx]); \
    const float4 h1B = *(const float4*)(&hp_s[1][(hx) + 4]); \
    float r; \
    r = __builtin_amdgcn_rcpf(__builtin_amdgcn_exp2f(h0A.x + f0) + 1.0f); ac00 = fmaf(wA.x, r, ac00); \
    r = __builtin_amdgcn_rcpf(__builtin_amdgcn_exp2f(h0A.y + f1) + 1.0f); ac01 = fmaf(wA.y, r, ac01); \
    r = __builtin_amdgcn_rcpf(__builtin_amdgcn_exp2f(h0A.z + f2) + 1.0f); ac00 = fmaf(wA.z, r, ac00); \
    r = __builtin_amdgcn_rcpf(__builtin_amdgcn_exp2f(h0A.w + f3) + 1.0f); ac01 = fmaf(wA.w, r, ac01); \
    r = __builtin_amdgcn_rcpf(__builtin_amdgcn_exp2f(h0B.x + f4) + 1.0f); ac00 = fmaf(wB.x, r, ac00); \
    r = __builtin_amdgcn_rcpf(__builtin_amdgcn_exp2f(h0B.y + f5) + 1.0f); ac01 = fmaf(wB.y, r, ac01); \
    r = __builtin_amdgcn_rcpf(__builtin_amdgcn_exp2f(h0B.z + f6) + 1.0f); ac00 = fmaf(wB.z, r, ac00); \
    r = __builtin_amdgcn_rcpf(__builtin_amdgcn_exp2f(h0B.w + f7) + 1.0f); ac01 = fmaf(wB.w, r, ac01); \
    r = __builtin_amdgcn_rcpf(__builtin_amdgcn_exp2f(h1A.x + f0) + 1.0f); ac10 = fmaf(wA.x, r, ac10); \
    r = __builtin_amdgcn_rcpf(__builtin_amdgcn_exp2f(h1A.y + f1) + 1.0f); ac11 = fmaf(wA.y, r, ac11); \
    r = __builtin_amdgcn_rcpf(__builtin_amdgcn_exp2f(h1A.z + f2) + 1.0f); ac10 = fmaf(wA.z, r, ac10); \
    r = __builtin_amdgcn_rcpf(__builtin_amdgcn_exp2f(h1A.w + f3) + 1.0f); ac11 = fmaf(wA.w, r, ac11); \
    r = __builtin_amdgcn_rcpf(__builtin_amdgcn_exp2f(h1B.x + f4) + 1.0f); ac10 = fmaf(wB.x, r, ac10); \
    r = __builtin_amdgcn_rcpf(__builtin_amdgcn_exp2f(h1B.y + f5) + 1.0f); ac11 = fmaf(wB.y, r, ac11); \
    r = __builtin_amdgcn_rcpf(__builtin_amdgcn_exp2f(h1B.z + f6) + 1.0f); ac10 = fmaf(wB.z, r, ac10); \
    r = __builtin_amdgcn_rcpf(__builtin_amdgcn_exp2f(h1B.w + f7) + 1.0f); ac11 = fmaf(wB.w, r, ac11); \
}

#define CONSUMEG4(R, g) \
    C1(R##0, hbase + ((g)*4+0)*8)  C1(R##1, hbase + ((g)*4+1)*8) \
    C1(R##2, hbase + ((g)*4+2)*8)  C1(R##3, hbase + ((g)*4+3)*8)

__global__ __launch_bounds__(512, 6)
void biaffine_loss(const float* __restrict__ hp_all,
                   const ushort* __restrict__ haTb,
                   const float* __restrict__ Wout,
                   const int* __restrict__ ng,
                   const int* __restrict__ att,
                   const float* __restrict__ target,
                   float* __restrict__ out_logits,
                   float* __restrict__ accum,
                   float* __restrict__ out_loss)
{
    __shared__ float hp_s[PT][Hh];
    __shared__ float wc_s[Hh];
    __shared__ float partial[PT][3][Ss];
    __shared__ float maskneg[PT][Ss];
    __shared__ float redmax[PT][2];
    __shared__ float red3[PT][2][3];
    __shared__ float swr_s;

    const int pt  = blockIdx.x / Cc;     // 0..127
    const int c   = blockIdx.x - pt * Cc;
    const int bp0 = pt * PT;
    const int b   = bp0 >> 7;
    const int tid = threadIdx.x;
    const int a   = tid & (Ss - 1);
    const int hq  = tid >> 7;            // 0..3: h-quarter (wave-pair uniform)
    const int lane = tid & 63;

    // stage hp rows + wc row into LDS (coalesced); mask
    for (int i = tid; i < PT * Hh; i += 512) ((float*)hp_s)[i] = hp_all[(size_t)bp0 * Hh + i];
    for (int i = tid; i < Hh; i += 512)      wc_s[i] = Wout[(size_t)c * Hh + i];
    if (tid < PT * Ss) {
        const int p_i = tid >> 7;
        const int aa  = tid & (Ss - 1);
        int any = 0;
        if (att[b * Ss + aa] > 0) {
            const int* ngp = ng + (size_t)(bp0 + p_i) * Cc * Ss + aa;
            #pragma unroll
            for (int cc = 0; cc < Cc; ++cc) any |= ngp[cc * Ss];
        }
        maskneg[p_i][aa] = any ? 0.0f : NEGV;
    }
    __syncthreads();

    if (tid < 64) {    // wave 0: sumW[c]
        float s = 0.f;
        #pragma unroll
        for (int i = 0; i < Hh / 64; ++i) s += wc_s[tid + i * 64];
        #pragma unroll
        for (int off = 32; off; off >>= 1) s += __shfl_xor(s, off, 64);
        if (tid == 0) swr_s = s;
    }

    // thread's ha stream: uint4 j (8 h each); index = (hq*24 + j)*128 + a
    const uint4* hap4 = (const uint4*)(haTb + ((size_t)(b * Cc + c) * 96) * 1024)
                      + (size_t)hq * 24 * 128 + a;
    const int hbase = hq * 192;

    uint4 A0, A1, A2, A3;
    uint4 B0, B1, B2, B3;
    float ac00 = 0.f, ac01 = 0.f, ac10 = 0.f, ac11 = 0.f;

    LOADG4(A, 0) SB
    LOADG4(B, 1) SB  CONSUMEG4(A, 0) SB
    LOADG4(A, 2) SB  CONSUMEG4(B, 1) SB
    LOADG4(B, 3) SB  CONSUMEG4(A, 2) SB
    LOADG4(A, 4) SB  CONSUMEG4(B, 3) SB
    LOADG4(B, 5) SB  CONSUMEG4(A, 4) SB
    CONSUMEG4(B, 5)

    if (hq != 0) {
        partial[0][hq - 1][a] = ac00 + ac01;
        partial[1][hq - 1][a] = ac10 + ac11;
    }
    __syncthreads();

    float logit[PT];
    const int wv = tid >> 6;             // 0/1 for hq==0 threads
    if (hq == 0) {
        const float ps[PT] = { ac00 + ac01, ac10 + ac11 };
        #pragma unroll
        for (int p = 0; p < PT; ++p) {
            const float full = ps[p] + partial[p][0][a] + partial[p][1][a] + partial[p][2][a];
            logit[p] = swr_s - 2.0f * full + maskneg[p][a];
            out_logits[((size_t)(bp0 + p) * Cc + c) * Ss + a] = logit[p];
            float mx = logit[p];
            #pragma unroll
            for (int off = 32; off; off >>= 1) mx = fmaxf(mx, __shfl_xor(mx, off, 64));
            if (lane == 0) redmax[p][wv] = mx;
        }
    }
    __syncthreads();

    if (hq == 0) {
        #pragma unroll
        for (int p = 0; p < PT; ++p) {
            const float rm = fmaxf(redmax[p][0], redmax[p][1]);
            const float e  = __builtin_amdgcn_exp2f((logit[p] - rm) * 1.4426950408889634f);
            const float tg = target[((size_t)(bp0 + p) * Cc + c) * Ss + a];
            float se = e, st = tg, sx = tg * logit[p];
            #pragma unroll
            for (int off = 32; off; off >>= 1) {
                se += __shfl_xor(se, off, 64);
                st += __shfl_xor(st, off, 64);
                sx += __shfl_xor(sx, off, 64);
            }
            if (lane == 0) { red3[p][wv][0] = se; red3[p][wv][1] = st; red3[p][wv][2] = sx; }
        }
    }
    __syncthreads();

    if (tid == 0) {
        float nsum = 0.f, dsum = 0.f;
        #pragma unroll
        for (int p = 0; p < PT; ++p) {
            const float rm = fmaxf(redmax[p][0], redmax[p][1]);
            const float SE = red3[p][0][0] + red3[p][1][0];
            const float ST = red3[p][0][1] + red3[p][1][1];
            const float SX = red3[p][0][2] + red3[p][1][2];
            const float lse = rm + __builtin_amdgcn_logf(SE) * 0.6931471805599453f;
            nsum += lse * ST - SX;
            dsum += ST;
        }
        atomicAdd(&accum[0], nsum);
        atomicAdd(&accum[1], dsum);
        __threadfence();
        const unsigned old = atomicAdd((unsigned*)(accum + 2), 1u);
        if (old == (unsigned)(NBLK - 1)) {          // last block: finalize loss
            const float n = atomicAdd(&accum[0], 0.0f);
            const float d = atomicAdd(&accum[1], 0.0f);
            out_loss[0] = n / d;
        }
    }
}

extern "C" void kernel_launch(void* const* d_in, const int* in_sizes, int n_in,
                              void* d_out, int out_size, void* d_ws, size_t ws_size,
                              hipStream_t stream) {
    const float* seq    = (const float*)d_in[0];
    const int*   att    = (const int*)  d_in[1];
    const int*   ng     = (const int*)  d_in[2];
    const float* target = (const float*)d_in[3];
    const float* Wprd   = (const float*)d_in[4];
    const float* bprd   = (const float*)d_in[5];
    const float* Warg   = (const float*)d_in[6];
    const float* barg   = (const float*)d_in[7];
    const float* Wout   = (const float*)d_in[8];

    float*  out    = (float*)d_out;
    float*  hp_out = (float*)d_ws;                       // 196608 floats
    ushort* haTb   = (ushort*)(hp_out + 196608);         // 983040 ushorts
    float*  accum  = hp_out + 196608 + 491520;           // 3 slots

    gemm_mfma<<<dim3(4, 144), 256, 0, stream>>>(seq, Wprd, Warg, bprd, barg,
                                                hp_out, haTb, accum);
    biaffine_loss<<<dim3(NBLK), 512, 0, stream>>>(hp_out, haTb, Wout, ng, att, target,
                                                  out + 1, accum, out);
}